// Round 1
// baseline (440.441 us; speedup 1.0000x reference)
//
#include <hip/hip_runtime.h>
#include <hip/hip_bf16.h>

typedef float f32x4 __attribute__((ext_vector_type(4)));
typedef __bf16 bf16x8 __attribute__((ext_vector_type(8)));
typedef short s16x8 __attribute__((ext_vector_type(8)));
typedef unsigned short u16;

#define HWSZ 16384
#define NPIX 131072

// ws byte offsets (total ~43.1 MB)
#define XT_OFF    0u          // float[NPIX*64]  x transposed to NHWC
#define OFFS_OFF  33554432u   // float[NPIX*18]  offset-conv output, [pix][18]
#define WB_OFF    42991616u   // u16[64*576]     deform_w as bf16, [o][k2*64+c]
#define OFFR_OFF  43065344u   // float[576*18]   offset_w reordered [k2*64+c][18]
#define STATS_OFF 43106816u   // float[256]: sums[64], sumsq[64], scale[64], shift[64]

// ---- prep: reorder/convert weights, zero BN stats ----
__global__ void kprep(const float* __restrict__ dw, const float* __restrict__ ow,
                      u16* __restrict__ Wb, float* __restrict__ offr,
                      float* __restrict__ stats) {
  int t = blockIdx.x * 256 + threadIdx.x;
  if (t < 256) stats[t] = 0.f;
  if (t < 36864) {                      // deform_w (64,64,3,3) -> Wb[o][k2*64+c] bf16
    int o = t / 576, r = t % 576;
    int c = r / 9, k2 = r % 9;
    __hip_bfloat16 h = __float2bfloat16(dw[t]);
    Wb[o * 576 + k2 * 64 + c] = __builtin_bit_cast(u16, h);
  } else if (t < 47232) {               // offset_w (18,64,3,3) -> offr[k2*64+c][18]
    int t2 = t - 36864;
    int oc = t2 / 576, r = t2 % 576;
    int c = r / 9, k2 = r % 9;
    offr[(k2 * 64 + c) * 18 + oc] = ow[t2];
  }
}

// ---- NCHW -> NHWC transpose of x ----
__global__ void ktrans(const float* __restrict__ x, float* __restrict__ xt) {
  __shared__ float tile[64][65];
  int blk = blockIdx.x;
  int b = blk >> 8, hwT = (blk & 255) * 64;
  int tx = threadIdx.x & 63, ty = threadIdx.x >> 6;
  const float* xp = x + (size_t)b * 64 * HWSZ;
#pragma unroll
  for (int r = 0; r < 16; ++r) {
    int c = r * 4 + ty;
    tile[c][tx] = xp[c * HWSZ + hwT + tx];
  }
  __syncthreads();
  float* xo = xt + ((size_t)b * HWSZ + hwT) * 64;
#pragma unroll
  for (int r = 0; r < 16; ++r) {
    int hwl = r * 4 + ty;
    xo[hwl * 64 + tx] = tile[tx][hwl];
  }
}

// ---- offset conv: 3x3, 64->18 ch, fp32, thread per pixel ----
__global__ void koffc(const float* __restrict__ xt, const float* __restrict__ offr,
                      const float* __restrict__ offb, float* __restrict__ offs) {
  int pix = blockIdx.x * 256 + threadIdx.x;
  int b = pix >> 14, hw = pix & 16383;
  int h = hw >> 7, w = hw & 127;
  float acc[18];
#pragma unroll
  for (int oc = 0; oc < 18; ++oc) acc[oc] = offb[oc];
#pragma unroll
  for (int k2 = 0; k2 < 9; ++k2) {
    int y = h - 1 + k2 / 3, x = w - 1 + k2 % 3;
    if ((unsigned)y < 128u && (unsigned)x < 128u) {
      const float* px = xt + (((b << 7) + y << 7) + x) * 64;
      const float* wr = offr + k2 * 64 * 18;
      for (int c = 0; c < 64; c += 4) {   // rolled: 16 iters x 72 FMA
        f32x4 xv = *(const f32x4*)(px + c);
#pragma unroll
        for (int j = 0; j < 4; ++j)
#pragma unroll
          for (int oc = 0; oc < 18; ++oc)
            acc[oc] = fmaf(wr[(c + j) * 18 + oc], xv[j], acc[oc]);
      }
    }
  }
  float* op = offs + (size_t)pix * 18;
#pragma unroll
  for (int oc = 0; oc < 18; ++oc) op[oc] = acc[oc];
}

// ---- deformable conv: bilinear sample into LDS (bf16) + MFMA GEMM ----
// block: 256 thr = 4 waves; tile = 64 o x 64 pixels; K = 576 (k2*64+c)
__global__ __launch_bounds__(256) void kdeform(
    const float* __restrict__ xt, const float* __restrict__ offs,
    const u16* __restrict__ Wb, const float* __restrict__ db,
    float* __restrict__ y, float* __restrict__ stats) {
  __shared__ u16 S[64 * 584];            // [pix][ck], stride 584 (16B-aligned, pads conflicts)
  int tid = threadIdx.x;
  int lane = tid & 63, wid = tid >> 6;
  int base = blockIdx.x * 64;
  int b = base >> 14;

  // sampling: wave wid handles pixels wid*16..+15; lane = channel
  for (int i = 0; i < 16; ++i) {
    int p = wid * 16 + i;
    int pix = base + p;
    int hw = pix & 16383;
    int h = hw >> 7, wx = hw & 127;
    const float* op = offs + (size_t)pix * 18;
#pragma unroll
    for (int k2 = 0; k2 < 9; ++k2) {
      float dy = op[2 * k2], dx = op[2 * k2 + 1];
      float sy = (float)(h - 1 + k2 / 3) + dy;
      float sx = (float)(wx - 1 + k2 % 3) + dx;
      float fy = floorf(sy), fx = floorf(sx);
      int y0 = (int)fy, x0 = (int)fx;
      float wy1 = sy - fy, wx1 = sx - fx;
      float wy0 = 1.f - wy1, wx0 = 1.f - wx1;
      int y1 = y0 + 1, x1 = x0 + 1;
      int rb = b << 14;
      bool vy0 = (unsigned)y0 < 128u, vy1 = (unsigned)y1 < 128u;
      bool vx0 = (unsigned)x0 < 128u, vx1 = (unsigned)x1 < 128u;
      float v00 = (vy0 && vx0) ? xt[(rb + (y0 << 7) + x0) * 64 + lane] : 0.f;
      float v01 = (vy0 && vx1) ? xt[(rb + (y0 << 7) + x1) * 64 + lane] : 0.f;
      float v10 = (vy1 && vx0) ? xt[(rb + (y1 << 7) + x0) * 64 + lane] : 0.f;
      float v11 = (vy1 && vx1) ? xt[(rb + (y1 << 7) + x1) * 64 + lane] : 0.f;
      float s = wy0 * (wx0 * v00 + wx1 * v01) + wy1 * (wx0 * v10 + wx1 * v11);
      __hip_bfloat16 hb = __float2bfloat16(s);
      S[p * 584 + k2 * 64 + lane] = __builtin_bit_cast(u16, hb);
    }
  }

  // A fragments: W rows for this wave's 16 output channels, K=576 in 18 steps
  bf16x8 af[18];
  const u16* wrow = Wb + (wid * 16 + (lane & 15)) * 576 + (lane >> 4) * 8;
#pragma unroll
  for (int kc = 0; kc < 18; ++kc)
    af[kc] = __builtin_bit_cast(bf16x8, *(const s16x8*)(wrow + kc * 32));

  __syncthreads();

  f32x4 zero = {0.f, 0.f, 0.f, 0.f};
  f32x4 acc[4];
#pragma unroll
  for (int nf = 0; nf < 4; ++nf) acc[nf] = zero;
#pragma unroll
  for (int kc = 0; kc < 18; ++kc) {
#pragma unroll
    for (int nf = 0; nf < 4; ++nf) {
      const u16* sp = &S[(nf * 16 + (lane & 15)) * 584 + kc * 32 + (lane >> 4) * 8];
      bf16x8 bfr = __builtin_bit_cast(bf16x8, *(const s16x8*)sp);
      acc[nf] = __builtin_amdgcn_mfma_f32_16x16x32_bf16(af[kc], bfr, acc[nf], 0, 0, 0);
    }
  }

  // epilogue: write y (NCHW) + per-channel partial sums
  int obase = wid * 16 + (lane >> 4) * 4;
  float s1[4] = {0, 0, 0, 0}, s2[4] = {0, 0, 0, 0};
#pragma unroll
  for (int nf = 0; nf < 4; ++nf) {
    int pix = base + nf * 16 + (lane & 15);
    int hw = pix & 16383;
    float* yp = y + (size_t)b * (64 * HWSZ) + hw;
#pragma unroll
    for (int r = 0; r < 4; ++r) {
      int o = obase + r;
      float v = acc[nf][r] + db[o];
      yp[(size_t)o * HWSZ] = v;
      s1[r] += v;
      s2[r] += v * v;
    }
  }
#pragma unroll
  for (int m = 1; m < 16; m <<= 1) {
#pragma unroll
    for (int r = 0; r < 4; ++r) {
      s1[r] += __shfl_xor(s1[r], m, 64);
      s2[r] += __shfl_xor(s2[r], m, 64);
    }
  }
  if ((lane & 15) == 0) {
#pragma unroll
    for (int r = 0; r < 4; ++r) {
      atomicAdd(&stats[obase + r], s1[r]);
      atomicAdd(&stats[64 + obase + r], s2[r]);
    }
  }
}

// ---- BN finalize: scale/shift per channel ----
__global__ void kbn(const float* __restrict__ gamma, const float* __restrict__ beta,
                    float* __restrict__ stats) {
  int o = threadIdx.x;
  if (o < 64) {
    float m = stats[o] * (1.f / 131072.f);
    float v = stats[64 + o] * (1.f / 131072.f) - m * m;
    float sc = gamma[o] * rsqrtf(v + 1e-5f);
    stats[128 + o] = sc;
    stats[192 + o] = beta[o] - m * sc;
  }
}

// ---- in-place scale/shift + PReLU on y (= d_out) ----
__global__ void kfinal(float* __restrict__ y, const float* __restrict__ stats,
                       const float* __restrict__ pa) {
  float a = pa[0];
  int total = NPIX * 64 / 4;
  for (int i = blockIdx.x * blockDim.x + threadIdx.x; i < total;
       i += gridDim.x * blockDim.x) {
    int o = (i >> 12) & 63;              // (i*4 >> 14) & 63
    f32x4 v = ((const f32x4*)y)[i];
    float sc = stats[128 + o], sh = stats[192 + o];
#pragma unroll
    for (int j = 0; j < 4; ++j) {
      float t = fmaf(v[j], sc, sh);
      v[j] = t >= 0.f ? t : a * t;
    }
    ((f32x4*)y)[i] = v;
  }
}

extern "C" void kernel_launch(void* const* d_in, const int* in_sizes, int n_in,
                              void* d_out, int out_size, void* d_ws, size_t ws_size,
                              hipStream_t stream) {
  const float* x  = (const float*)d_in[0];
  const float* ow = (const float*)d_in[1];
  const float* ob = (const float*)d_in[2];
  const float* dw = (const float*)d_in[3];
  const float* db = (const float*)d_in[4];
  const float* gm = (const float*)d_in[5];
  const float* bt = (const float*)d_in[6];
  const float* pa = (const float*)d_in[7];
  char* ws = (char*)d_ws;
  float* xt    = (float*)(ws + XT_OFF);
  float* offs  = (float*)(ws + OFFS_OFF);
  u16*   Wb    = (u16*)(ws + WB_OFF);
  float* offr  = (float*)(ws + OFFR_OFF);
  float* stats = (float*)(ws + STATS_OFF);
  float* y = (float*)d_out;   // use d_out as the pre-BN activation buffer

  kprep<<<185, 256, 0, stream>>>(dw, ow, Wb, offr, stats);
  ktrans<<<2048, 256, 0, stream>>>(x, xt);
  koffc<<<512, 256, 0, stream>>>(xt, offr, ob, offs);
  kdeform<<<2048, 256, 0, stream>>>(xt, offs, Wb, db, y, stats);
  kbn<<<1, 64, 0, stream>>>(gm, bt, stats);
  kfinal<<<2048, 256, 0, stream>>>(y, stats, pa);
}